// Round 14
// baseline (1806.696 us; speedup 1.0000x reference)
//
#include <hip/hip_runtime.h>

#define N_NODES 100000
#define D 64
#define N_EDGES 1000000
#define TILE 32
#define NTILES (N_NODES / TILE)   // 3125 exactly, no partial tiles

// ---- pass A: in-degree count ----
__global__ __launch_bounds__(256) void count_kernel(
    const int* __restrict__ dst, int* __restrict__ cnt) {
    int t = blockIdx.x * blockDim.x + threadIdx.x;
    int nt = gridDim.x * blockDim.x;
    for (int e = t; e < N_EDGES; e += nt) atomicAdd(&cnt[dst[e]], 1);
}

// ---- pass B: segment offsets. Wave-local prefix sum + ONE atomic per wave.
__global__ __launch_bounds__(256) void scan_kernel(
    const int* __restrict__ cnt, int* __restrict__ offset,
    int* __restrict__ wcur, int* __restrict__ total) {
    int n = blockIdx.x * blockDim.x + threadIdx.x;
    int lane = threadIdx.x & 63;
    int c = (n < N_NODES) ? cnt[n] : 0;
    int pre = c;
#pragma unroll
    for (int off = 1; off < 64; off <<= 1) {
        int t = __shfl_up(pre, off);
        if (lane >= off) pre += t;
    }
    int base = 0;
    if (lane == 63) base = atomicAdd(total, pre);  // lane63's pre == wave sum
    base = __shfl(base, 63);
    if (n < N_NODES) {
        int o = base + pre - c;  // exclusive
        offset[n] = o;
        wcur[n] = o;
    }
}

// ---- pass C: fill CSR ----
__global__ __launch_bounds__(256) void fill_kernel(
    const int* __restrict__ src, const int* __restrict__ dst,
    int* __restrict__ wcur, int* __restrict__ binned) {
    int t = blockIdx.x * blockDim.x + threadIdx.x;
    int nt = gridDim.x * blockDim.x;
    for (int e = t; e < N_EDGES; e += nt) {
        int pos = atomicAdd(&wcur[dst[e]], 1);
        binned[pos] = src[e];
    }
}

// ---- aggregation: one wave per node, register accumulation, mean folded in.
__global__ __launch_bounds__(256) void agg_kernel(
    const float* __restrict__ feat, const int* __restrict__ binned,
    const int* __restrict__ offset, const int* __restrict__ cnt,
    float* __restrict__ mean_out) {
    int wave = (blockIdx.x * blockDim.x + threadIdx.x) >> 6;
    int lane = threadIdx.x & 63;
    int nw = (gridDim.x * blockDim.x) >> 6;
    for (int n = wave; n < N_NODES; n += nw) {
        int c = cnt[n];
        int o = offset[n];
        float a0 = 0.f, a1 = 0.f, a2 = 0.f, a3 = 0.f;
        int i = 0;
        for (; i + 3 < c; i += 4) {
            int s0 = binned[o + i], s1 = binned[o + i + 1];
            int s2 = binned[o + i + 2], s3 = binned[o + i + 3];
            a0 += feat[((size_t)s0 << 6) + lane];
            a1 += feat[((size_t)s1 << 6) + lane];
            a2 += feat[((size_t)s2 << 6) + lane];
            a3 += feat[((size_t)s3 << 6) + lane];
        }
        for (; i < c; ++i) a0 += feat[((size_t)binned[o + i] << 6) + lane];
        float m = (a0 + a1) + (a2 + a3);
        m = (c > 0) ? m / (float)c : 0.f;
        mean_out[((size_t)n << 6) + lane] = m;
    }
}

// ---- fused transform, LDS-tiled ----
// Block = one 32-node tile. Stage mean-tile + x-tile (contiguous 8 KB each)
// via coalesced float4 -> LDS. Wave w computes nodes [w*8, w*8+8): lane j
// holds W column j (64 VGPR), rows broadcast from LDS (uniform ds_read_b128,
// conflict-free). Two sequential k-loops reuse the SAME wcol regs (Wl then
// Wr) -> peak ~93 VGPR, no spill. acc[8] statically indexed (full unroll).
// out[n][j] = relu(mean[n]@Wl + x[n]@Wr + b)[j]; FUSE_OUT adds @Wc + bc.
template <bool FUSE_OUT>
__global__ __launch_bounds__(256, 4) void transform_kernel(
    const float* __restrict__ mean, const float* __restrict__ xin,
    const float* __restrict__ Wl, const float* __restrict__ Wr,
    const float* __restrict__ bias,
    const float* __restrict__ Wc, const float* __restrict__ bc,
    float* __restrict__ out) {
    __shared__ float sm[TILE * D];   // 8 KB
    __shared__ float sx[TILE * D];   // 8 KB
    int tid = threadIdx.x;
    int lane = tid & 63, wave = tid >> 6;
    int tile = blockIdx.x;

    // stage both tiles: contiguous 2048 floats each -> 2 coalesced float4/thread
    const float4* gm = (const float4*)mean + (size_t)tile * (TILE * D / 4);
    const float4* gx = (const float4*)xin + (size_t)tile * (TILE * D / 4);
    ((float4*)sm)[tid] = gm[tid];
    ((float4*)sm)[tid + 256] = gm[tid + 256];
    ((float4*)sx)[tid] = gx[tid];
    ((float4*)sx)[tid + 256] = gx[tid + 256];

    float bj = bias[lane];
    float wcj = FUSE_OUT ? Wc[lane] : 0.f;
    float bcv = FUSE_OUT ? bc[0] : 0.f;
    __syncthreads();

    float acc[8];
    {   // loop 1: mean @ Wl
        float wcol[64];
#pragma unroll
        for (int k = 0; k < 64; ++k) wcol[k] = Wl[k * 64 + lane];
#pragma unroll
        for (int mm = 0; mm < 8; ++mm) {
            const float4* row = (const float4*)(sm + (wave * 8 + mm) * D);
            float a0 = 0.f, a1 = 0.f;
#pragma unroll
            for (int c = 0; c < 16; c += 2) {
                float4 v0 = row[c];
                float4 v1 = row[c + 1];
                a0 = fmaf(v0.x, wcol[4 * c + 0], a0);
                a0 = fmaf(v0.y, wcol[4 * c + 1], a0);
                a0 = fmaf(v0.z, wcol[4 * c + 2], a0);
                a0 = fmaf(v0.w, wcol[4 * c + 3], a0);
                a1 = fmaf(v1.x, wcol[4 * c + 4], a1);
                a1 = fmaf(v1.y, wcol[4 * c + 5], a1);
                a1 = fmaf(v1.z, wcol[4 * c + 6], a1);
                a1 = fmaf(v1.w, wcol[4 * c + 7], a1);
            }
            acc[mm] = a0 + a1;
        }
    }
    {   // loop 2: + x @ Wr  (reload wcol -> same registers, no pressure spike)
        float wcol[64];
#pragma unroll
        for (int k = 0; k < 64; ++k) wcol[k] = Wr[k * 64 + lane];
#pragma unroll
        for (int mm = 0; mm < 8; ++mm) {
            const float4* row = (const float4*)(sx + (wave * 8 + mm) * D);
            float a0 = 0.f, a1 = 0.f;
#pragma unroll
            for (int c = 0; c < 16; c += 2) {
                float4 v0 = row[c];
                float4 v1 = row[c + 1];
                a0 = fmaf(v0.x, wcol[4 * c + 0], a0);
                a0 = fmaf(v0.y, wcol[4 * c + 1], a0);
                a0 = fmaf(v0.z, wcol[4 * c + 2], a0);
                a0 = fmaf(v0.w, wcol[4 * c + 3], a0);
                a1 = fmaf(v1.x, wcol[4 * c + 4], a1);
                a1 = fmaf(v1.y, wcol[4 * c + 5], a1);
                a1 = fmaf(v1.z, wcol[4 * c + 6], a1);
                a1 = fmaf(v1.w, wcol[4 * c + 7], a1);
            }
            acc[mm] += a0 + a1;
        }
    }
    // epilogue: bias + relu (+ classifier)
#pragma unroll
    for (int mm = 0; mm < 8; ++mm) {
        int n = tile * TILE + wave * 8 + mm;
        float h = fmaxf(acc[mm] + bj, 0.f);
        if (FUSE_OUT) {
            float v = h * wcj;
#pragma unroll
            for (int off = 32; off; off >>= 1) v += __shfl_xor(v, off);
            if (lane == 0) out[n] = v + bcv;
        } else {
            out[((size_t)n << 6) + lane] = h;
        }
    }
}

extern "C" void kernel_launch(void* const* d_in, const int* in_sizes, int n_in,
                              void* d_out, int out_size, void* d_ws, size_t ws_size,
                              hipStream_t stream) {
    const float* x   = (const float*)d_in[0];
    const int* ei    = (const int*)d_in[1];  // [2, N_EDGES] int32
    const float* W1l = (const float*)d_in[2];
    const float* W1r = (const float*)d_in[3];
    const float* b1  = (const float*)d_in[4];
    const float* W2l = (const float*)d_in[5];
    const float* W2r = (const float*)d_in[6];
    const float* b2  = (const float*)d_in[7];
    const float* Wc  = (const float*)d_in[8];
    const float* bc  = (const float*)d_in[9];
    float* out = (float*)d_out;

    const int* src = ei;
    const int* dst = ei + N_EDGES;

    // ws: cnt i32[N] | total i32[16] | offset i32[N] | wcur i32[N]
    //     | binned i32[E] | meanbuf f32[N*D] | h1 f32[N*D]   => ~56.5 MB
    char* w = (char*)d_ws;
    int*   cnt     = (int*)w;      w += (size_t)N_NODES * 4;
    int*   total   = (int*)w;      w += 16 * 4;
    int*   offset  = (int*)w;      w += (size_t)N_NODES * 4;
    int*   wcur    = (int*)w;      w += (size_t)N_NODES * 4;
    int*   binned  = (int*)w;      w += (size_t)N_EDGES * 4;
    float* meanbuf = (float*)w;    w += (size_t)N_NODES * D * 4;
    float* h1      = (float*)w;

    // ---- build CSR once (shared by both layers) ----
    hipMemsetAsync(cnt, 0, ((size_t)N_NODES + 16) * 4, stream);  // cnt + total
    count_kernel<<<2048, 256, 0, stream>>>(dst, cnt);
    scan_kernel<<<(N_NODES + 255) / 256, 256, 0, stream>>>(cnt, offset, wcur, total);
    fill_kernel<<<2048, 256, 0, stream>>>(src, dst, wcur, binned);

    // ---- layer 1 ----
    agg_kernel<<<2048, 256, 0, stream>>>(x, binned, offset, cnt, meanbuf);
    transform_kernel<false><<<NTILES, 256, 0, stream>>>(
        meanbuf, x, W1l, W1r, b1, nullptr, nullptr, h1);

    // ---- layer 2 + fused classifier ----
    agg_kernel<<<2048, 256, 0, stream>>>(h1, binned, offset, cnt, meanbuf);
    transform_kernel<true><<<NTILES, 256, 0, stream>>>(
        meanbuf, h1, W2l, W2r, b2, Wc, bc, out);
}